// Round 1
// 1238.566 us; speedup vs baseline: 1.0152x; 1.0152x over previous
//
#include <hip/hip_runtime.h>
#include <math.h>

#define NNODES 40000
#define NEDGES 640000
#define NPB 8             // nodes per edge-block
#define LROW 257          // padded LDS accumulator row stride (floats)

typedef __attribute__((ext_vector_type(8))) short short8_t;
typedef __attribute__((ext_vector_type(4))) float float4_t;

__device__ __forceinline__ float4 ld4(const float* p) { return *(const float4*)p; }

__device__ __forceinline__ unsigned short bf16r(float x) {
  union { float f; unsigned u; } v; v.f = x;
  unsigned u = v.u;
  u += 0x7FFFu + ((u >> 16) & 1u);   // RNE
  return (unsigned short)(u >> 16);
}

__device__ __forceinline__ void lds_fadd(float* p, float v) {
  __hip_atomic_fetch_add(p, v, __ATOMIC_RELAXED, __HIP_MEMORY_SCOPE_WORKGROUP);
}

#define INV_SQRT3_C 0.57735026918962576f

// 8 LDS atomics for one (edge-row, u) pair. All operands scalar -> static regs.
__device__ __forceinline__ void accum_half(float* lrow, int u,
    float w0, float w1, float w2, float w3,
    float se, float vx, float vy, float vz,
    float esc, float ev0, float ev1, float ev2) {
  lds_fadd(lrow + u, w0 * se * esc);
  float dv = vx * ev0 + vy * ev1 + vz * ev2;
  lds_fadd(lrow + 32 + u, w3 * dv * INV_SQRT3_C);
  float b1v = w1 * se;
  lds_fadd(lrow + 64 + u * 3 + 0, b1v * ev0);
  lds_fadd(lrow + 64 + u * 3 + 1, b1v * ev1);
  lds_fadd(lrow + 64 + u * 3 + 2, b1v * ev2);
  float b2v = w2 * esc;
  lds_fadd(lrow + 160 + u * 3 + 0, b2v * vx);
  lds_fadd(lrow + 160 + u * 3 + 1, b2v * vy);
  lds_fadd(lrow + 160 + u * 3 + 2, b2v * vz);
}

struct RowData { float se0, se1, vx0, vy0, vz0, vx1, vy1, vz1; };

__device__ __forceinline__ RowData load_row(const float* ab, int m) {
  RowData d;
  d.se0 = ab[m];            d.se1 = ab[m + 16];
  d.vx0 = ab[32 + 3 * m];   d.vy0 = ab[33 + 3 * m];   d.vz0 = ab[34 + 3 * m];
  d.vx1 = ab[80 + 3 * m];   d.vy1 = ab[81 + 3 * m];   d.vz1 = ab[82 + 3 * m];
  return d;
}

// ---------------- Stage 1: s' = s @ W1s/sqrt(32); v' = einsum(v, W1v)/sqrt(32)
__global__ void k1_stage1(const float* __restrict__ node_input,
                          const float* __restrict__ w1s,
                          const float* __restrict__ w1v,
                          float* __restrict__ A) {
  const float scale = 0.17677669529663687f; // 1/sqrt(32)
  int stride = gridDim.x * blockDim.x;
  for (int idx = blockIdx.x * blockDim.x + threadIdx.x; idx < NNODES * 128; idx += stride) {
    int n = idx >> 7;
    int c = idx & 127;
    const float* row = node_input + n * 128;
    float acc = 0.f;
    if (c < 32) {
      #pragma unroll
      for (int u = 0; u < 32; ++u)
        acc = fmaf(row[u], w1s[u * 32 + c], acc);
    } else {
      int cc = c - 32;
      int w = cc / 3;
      int i = cc - w * 3;
      #pragma unroll
      for (int u = 0; u < 32; ++u)
        acc = fmaf(row[32 + u * 3 + i], w1v[u * 32 + w], acc);
    }
    A[idx] = acc * scale;
  }
}

// ---------------- CSR build (proven, byte-identical) ----------------
__global__ void k_hist(const int* __restrict__ edge_dst, int* __restrict__ counts) {
  int e = blockIdx.x * blockDim.x + threadIdx.x;
  if (e < NEDGES) atomicAdd(&counts[edge_dst[e]], 1);
}

__global__ void k_scanA(const int* __restrict__ counts, int* __restrict__ bsum) {
  __shared__ int ws[4];
  int t = blockIdx.x * 256 + threadIdx.x;
  int v = (t < NNODES) ? counts[t] : 0;
  for (int d = 32; d; d >>= 1) v += __shfl_down(v, d, 64);
  if ((threadIdx.x & 63) == 0) ws[threadIdx.x >> 6] = v;
  __syncthreads();
  if (threadIdx.x == 0) bsum[blockIdx.x] = ws[0] + ws[1] + ws[2] + ws[3];
}

__global__ __launch_bounds__(256) void k_scanB(const int* __restrict__ bsum,
                                               int* __restrict__ boff,
                                               int* __restrict__ offsets) {
  __shared__ int s[256];
  int tid = threadIdx.x;
  int v = (tid < 157) ? bsum[tid] : 0;
  s[tid] = v;
  __syncthreads();
  for (int d = 1; d < 256; d <<= 1) {
    int x = (tid >= d) ? s[tid - d] : 0;
    __syncthreads();
    s[tid] += x;
    __syncthreads();
  }
  if (tid < 157) boff[tid] = s[tid] - v;
  if (tid == 0) offsets[NNODES] = NEDGES;
}

__global__ __launch_bounds__(256) void k_scanC(const int* __restrict__ counts,
                                               const int* __restrict__ boff,
                                               int* __restrict__ offsets,
                                               int* __restrict__ cursor) {
  __shared__ int s[256];
  int tid = threadIdx.x;
  int t = blockIdx.x * 256 + tid;
  int v = (t < NNODES) ? counts[t] : 0;
  s[tid] = v;
  __syncthreads();
  for (int d = 1; d < 256; d <<= 1) {
    int x = (tid >= d) ? s[tid - d] : 0;
    __syncthreads();
    s[tid] += x;
    __syncthreads();
  }
  int off = boff[blockIdx.x] + s[tid] - v;
  if (t < NNODES) { offsets[t] = off; cursor[t] = off; }
}

__global__ void k_scatter(const int* __restrict__ edge_dst,
                          int* __restrict__ cursor, int* __restrict__ slots) {
  int e = blockIdx.x * blockDim.x + threadIdx.x;
  if (e < NEDGES) {
    int d = edge_dst[e];
    int p = atomicAdd(&cursor[d], 1);
    slots[p] = e;
  }
}

// ---------------- Fused edge kernel — R4: wave-independent main loop ----------
// Counters said: MfmaUtil 0.55%, VALUBusy 6.7%, HBM 4.5% -> pure latency bound,
// ~0.5 outstanding loads per wave. Changes vs R3+:
// (1) NO barriers in the main loop. Each wave owns chunk-edges {4m+wv} and
//     computes its A-fragments entirely in registers: lane (m,q) computes
//     h[edge 4m+wv][k = q*8+jj] (a0) and [k = 32+q*8+jj] (a1) -> exactly the
//     mfma_16x16x32 A-frag layout. h_frag LDS + both __syncthreads removed;
//     waves stall independently -> latency overlapped across 16-20 waves/CU.
// (2) Epilogue split into load-phase / atomic-phase: A-row gathers for edges
//     0,1 issue BEFORE the MFMA block (MFMA hides latency), edges 2,3 issue
//     before any LDS atomic -> 8-16 loads in flight per wave instead of ~4
//     interleaved with atomics.
// (3) Metadata (src, ln, edge_attr) crosses lanes via __shfl (ds_bpermute),
//     not LDS staging -> no ordering hazard without barriers.
// (4) w1 in bank-padded LDS (float4 groups, stride 18): q-groups land on
//     banks 8q apart -> conflict-free broadcast reads.
// Epilogue edge map unchanged from R3: C reg (q,r) -> chunk-edge 16q+4r+wv
// (16 apart across q-groups -> no same-address atomic serialization).
// ACC row (256 floats/node): [0..31] s0 | [32..63] s1 | [64..159] v0 | [160..255] v1
__global__ __launch_bounds__(256, 4) void k_edge(
    const float* __restrict__ A,
    const int* __restrict__ edge_src,
    const int* __restrict__ edge_dst,
    const float* __restrict__ edge_attr,
    const float* __restrict__ edge_scalars,
    const float* __restrict__ fc_w1,
    const float* __restrict__ fc_w2,
    const int* __restrict__ offsets,
    const int* __restrict__ slots,
    float* __restrict__ ACC) {
  const float INV_SQRT8 = 0.35355339059327373f;
  const float H_SCALE   = 1.6791767923989418f / 8.0f; // SILU_NORM / sqrt(64)

  __shared__ float    lacc[NPB * LROW];
  __shared__ short8_t w2frag[16 * 64];  // [(ctile*2+kh)*64 + lane]: B-frag-ready w2
  __shared__ float4   w1f[144];         // padded: col j, half hf -> (j>>3)*18+(j&7)*2+hf

  int tid = threadIdx.x;
  int n0 = blockIdx.x * NPB;
  int ebase = offsets[n0];
  int eend  = offsets[n0 + NPB];

  for (int i = tid; i < NPB * LROW; i += 256) lacc[i] = 0.f;
  if (tid < 128) {
    int j = tid >> 1, hf = tid & 1;
    float4 wv4;
    wv4.x = fc_w1[(hf * 4 + 0) * 64 + j] * INV_SQRT8;
    wv4.y = fc_w1[(hf * 4 + 1) * 64 + j] * INV_SQRT8;
    wv4.z = fc_w1[(hf * 4 + 2) * 64 + j] * INV_SQRT8;
    wv4.w = fc_w1[(hf * 4 + 3) * 64 + j] * INV_SQRT8;
    w1f[(j >> 3) * 18 + (j & 7) * 2 + hf] = wv4;
  }
  // B-frag layout (proven): frag f=(ct*2+kh), lane l holds
  // elem j = w2[k = kh*32 + (l>>4)*8 + j][c = ct*16 + (l&15)]
  for (int fi = tid; fi < 16 * 64; fi += 256) {
    int f = fi >> 6, ll = fi & 63;
    int ct = f >> 1, kh = f & 1, mm = ll & 15, qq = ll >> 4;
    short8_t v;
    #pragma unroll
    for (int j = 0; j < 8; ++j)
      v[j] = (short)bf16r(fc_w2[(kh * 32 + qq * 8 + j) * 128 + ct * 16 + mm]);
    w2frag[fi] = v;
  }
  __syncthreads();

  int wv = tid >> 6;       // wave id 0..3
  int l  = tid & 63;
  int m  = l & 15;
  int q  = l >> 4;

  for (int k0 = ebase; k0 < eend; k0 += 64) {
    // ---- phase 1 (per-wave, barrier-free): lane (m,q) handles chunk-edge 4m+wv
    int ce = k0 + 4 * m + wv;
    bool vld = ce < eend;
    int e = slots[vld ? ce : (eend - 1)];
    int srcm = edge_src[e];
    int lnm  = edge_dst[e] - n0;
    float4 eam = ld4(edge_attr + (long)e * 4);
    float4 sA = ld4(edge_scalars + (long)e * 8);
    float4 sB = ld4(edge_scalars + (long)e * 8 + 4);
    float es0 = sA.x, es1 = sA.y, es2 = sA.z, es3 = sA.w;
    float es4 = sB.x, es5 = sB.y, es6 = sB.z, es7 = sB.w;

    short8_t a0, a1;
    #pragma unroll
    for (int jj = 0; jj < 8; ++jj) {
      // k = q*8+jj  (columns of fc hidden, first k-half)
      float4 wA = w1f[q * 18 + jj * 2 + 0];
      float4 wB = w1f[q * 18 + jj * 2 + 1];
      float x = es0 * wA.x + es1 * wA.y + es2 * wA.z + es3 * wA.w
              + es4 * wB.x + es5 * wB.y + es6 * wB.z + es7 * wB.w;
      float hv = vld ? (x * H_SCALE) / (1.f + __expf(-x)) : 0.f;
      a0[jj] = (short)bf16r(hv);
      // k = 32 + q*8+jj  (second k-half)
      float4 wC = w1f[(4 + q) * 18 + jj * 2 + 0];
      float4 wD = w1f[(4 + q) * 18 + jj * 2 + 1];
      float x2 = es0 * wC.x + es1 * wC.y + es2 * wC.z + es3 * wC.w
               + es4 * wD.x + es5 * wD.y + es6 * wD.z + es7 * wD.w;
      float hv2 = vld ? (x2 * H_SCALE) / (1.f + __expf(-x2)) : 0.f;
      a1[jj] = (short)bf16r(hv2);
    }

    // ---- epilogue metadata: rows p=4q..4q+3 held by lanes p (m=p). __shfl.
    int sl0 = q * 4, sl1 = sl0 + 1, sl2 = sl0 + 2, sl3 = sl0 + 3;
    int src0 = __shfl(srcm, sl0, 64), src1 = __shfl(srcm, sl1, 64);
    int src2 = __shfl(srcm, sl2, 64), src3 = __shfl(srcm, sl3, 64);
    int ln0 = __shfl(lnm, sl0, 64), ln1 = __shfl(lnm, sl1, 64);
    int ln2 = __shfl(lnm, sl2, 64), ln3 = __shfl(lnm, sl3, 64);
    float ea0x = __shfl(eam.x, sl0, 64), ea0y = __shfl(eam.y, sl0, 64),
          ea0z = __shfl(eam.z, sl0, 64), ea0w = __shfl(eam.w, sl0, 64);
    float ea1x = __shfl(eam.x, sl1, 64), ea1y = __shfl(eam.y, sl1, 64),
          ea1z = __shfl(eam.z, sl1, 64), ea1w = __shfl(eam.w, sl1, 64);
    float ea2x = __shfl(eam.x, sl2, 64), ea2y = __shfl(eam.y, sl2, 64),
          ea2z = __shfl(eam.z, sl2, 64), ea2w = __shfl(eam.w, sl2, 64);
    float ea3x = __shfl(eam.x, sl3, 64), ea3y = __shfl(eam.y, sl3, 64),
          ea3z = __shfl(eam.z, sl3, 64), ea3w = __shfl(eam.w, sl3, 64);

    // ---- issue A-row gathers for rows 0,1 (latency hidden under MFMA)
    const float* abA = A + (long)src0 * 128;
    const float* abB = A + (long)src1 * 128;
    RowData dA = load_row(abA, m);
    RowData dB = load_row(abB, m);

    // ---- MFMA: w = h @ w2 for this wave's 16 edges
    float4_t acc[8];
    #pragma unroll
    for (int t = 0; t < 8; ++t) {
      short8_t b0 = w2frag[(t * 2 + 0) * 64 + l];
      short8_t b1 = w2frag[(t * 2 + 1) * 64 + l];
      float4_t z = (float4_t){0.f, 0.f, 0.f, 0.f};
      z = __builtin_amdgcn_mfma_f32_16x16x32_bf16(a0, b0, z, 0, 0, 0);
      z = __builtin_amdgcn_mfma_f32_16x16x32_bf16(a1, b1, z, 0, 0, 0);
      acc[t] = z;
    }

    // ---- issue A-row gathers for rows 2,3 BEFORE any atomic
    const float* abC = A + (long)src2 * 128;
    const float* abD = A + (long)src3 * 128;
    RowData dC = load_row(abC, m);
    RowData dD = load_row(abD, m);

    // ---- accumulate: C reg (q,r) -> tile row 4q+r -> chunk-edge 16q+4r+wv
    #define ACCUM_ROW(RR, LN, EAX, EAY, EAZ, EAW, D) do {                        \
        float* lrow = lacc + (LN) * LROW;                                        \
        accum_half(lrow, m,      acc[0][RR], acc[2][RR], acc[4][RR], acc[6][RR], \
                   D.se0, D.vx0, D.vy0, D.vz0, EAX, EAY, EAZ, EAW);              \
        accum_half(lrow, m + 16, acc[1][RR], acc[3][RR], acc[5][RR], acc[7][RR], \
                   D.se1, D.vx1, D.vy1, D.vz1, EAX, EAY, EAZ, EAW);              \
      } while (0)

    if (k0 + 64 <= eend) {
      ACCUM_ROW(0, ln0, ea0x, ea0y, ea0z, ea0w, dA);
      ACCUM_ROW(1, ln1, ea1x, ea1y, ea1z, ea1w, dB);
      ACCUM_ROW(2, ln2, ea2x, ea2y, ea2z, ea2w, dC);
      ACCUM_ROW(3, ln3, ea3x, ea3y, ea3z, ea3w, dD);
    } else {
      int cb = k0 + 16 * q + wv;
      if (cb + 0  < eend) ACCUM_ROW(0, ln0, ea0x, ea0y, ea0z, ea0w, dA);
      if (cb + 4  < eend) ACCUM_ROW(1, ln1, ea1x, ea1y, ea1z, ea1w, dB);
      if (cb + 8  < eend) ACCUM_ROW(2, ln2, ea2x, ea2y, ea2z, ea2w, dC);
      if (cb + 12 < eend) ACCUM_ROW(3, ln3, ea3x, ea3y, ea3z, ea3w, dD);
    }
    #undef ACCUM_ROW
  }
  __syncthreads();

  // write NPB node rows (coalesced); fully covers ACC (no memset needed)
  for (int i = tid; i < NPB * 256; i += 256) {
    int node = i >> 8;
    int c = i & 255;
    ACC[(long)(n0 + node) * 256 + c] = lacc[node * LROW + c];
  }
}

// ---------------- Stage 2: out_s = ns @ W2s; out_v = einsum(nv, W2v); scale 0.25/8
__global__ void k3_stage2(const float* __restrict__ ACC,
                          const float* __restrict__ w2s,
                          const float* __restrict__ w2v,
                          float* __restrict__ out) {
  const float scale = 0.03125f; // (1/sqrt(16)) / sqrt(64)
  int stride = gridDim.x * blockDim.x;
  for (int idx = blockIdx.x * blockDim.x + threadIdx.x; idx < NNODES * 128; idx += stride) {
    int n = idx >> 7;
    int c = idx & 127;
    const float* row = ACC + (long)n * 256;
    float acc = 0.f;
    if (c < 32) {
      #pragma unroll
      for (int qq = 0; qq < 64; ++qq)
        acc = fmaf(row[qq], w2s[qq * 32 + c], acc);
    } else {
      int cc = c - 32;
      int w = cc / 3;
      int i = cc - w * 3;
      #pragma unroll
      for (int qq = 0; qq < 64; ++qq)
        acc = fmaf(row[64 + qq * 3 + i], w2v[qq * 32 + w], acc);
    }
    out[idx] = acc * scale;
  }
}

extern "C" void kernel_launch(void* const* d_in, const int* in_sizes, int n_in,
                              void* d_out, int out_size, void* d_ws, size_t ws_size,
                              hipStream_t stream) {
  const float* node_input   = (const float*)d_in[0];
  const int*   edge_src     = (const int*)d_in[2];
  const int*   edge_dst     = (const int*)d_in[3];
  const float* edge_attr    = (const float*)d_in[4];
  const float* edge_scalars = (const float*)d_in[5];
  const float* w_lin1_s     = (const float*)d_in[6];
  const float* w_lin1_v     = (const float*)d_in[7];
  const float* fc_w1        = (const float*)d_in[8];
  const float* fc_w2        = (const float*)d_in[9];
  const float* w_lin2_s     = (const float*)d_in[10];
  const float* w_lin2_v     = (const float*)d_in[11];

  float* out = (float*)d_out;
  float* Abuf = out;  // stage-1 output lives in d_out; k3 overwrites it after k_edge

  // ws layout — identical footprint to the proven build
  char* p = (char*)d_ws;
  float* ACC    = (float*)p;  p += (size_t)NNODES * 256 * sizeof(float);
  int* counts   = (int*)p;    p += (size_t)NNODES * sizeof(int);
  int* offsets  = (int*)p;    p += (size_t)(NNODES + 4) * sizeof(int);
  int* cursor   = (int*)p;    p += (size_t)NNODES * sizeof(int);
  int* slots    = (int*)p;    p += (size_t)NEDGES * sizeof(int);
  int* bsum     = (int*)p;    p += 160 * sizeof(int);
  int* boff     = (int*)p;    p += 160 * sizeof(int);

  hipMemsetAsync(counts, 0, (size_t)NNODES * sizeof(int), stream);

  k1_stage1<<<2048, 256, 0, stream>>>(node_input, w_lin1_s, w_lin1_v, Abuf);
  k_hist<<<NEDGES / 256, 256, 0, stream>>>(edge_dst, counts);
  k_scanA<<<157, 256, 0, stream>>>(counts, bsum);
  k_scanB<<<1, 256, 0, stream>>>(bsum, boff, offsets);
  k_scanC<<<157, 256, 0, stream>>>(counts, boff, offsets, cursor);
  k_scatter<<<NEDGES / 256, 256, 0, stream>>>(edge_dst, cursor, slots);
  k_edge<<<NNODES / NPB, 256, 0, stream>>>(Abuf, edge_src, edge_dst, edge_attr,
                                           edge_scalars, fc_w1, fc_w2,
                                           offsets, slots, ACC);
  k3_stage2<<<2048, 256, 0, stream>>>(ACC, w_lin2_s, w_lin2_v, out);
}